// Round 7
// baseline (766.581 us; speedup 1.0000x reference)
//
#include <hip/hip_runtime.h>

typedef _Float16 HALF;
typedef _Float16 f16x8 __attribute__((ext_vector_type(8)));
typedef float f32x4 __attribute__((ext_vector_type(4)));
typedef int i32x4 __attribute__((ext_vector_type(4)));

// ---- fused weight conversion: fp32 (27*CI, CO) -> fp16 tiled [KP/32][CO_PAD][32], zero padded
struct WArgs { const float* W[8]; HALF* dst[8]; };

__global__ void convert_all_w_kernel(WArgs a)
{
    const int CIs[8]  = {64, 64, 64, 64, 32, 32, 16, 16};
    const int COs[8]  = {64, 64, 64, 32, 32, 16, 16, 3};
    const int COPs[8] = {64, 64, 64, 32, 32, 16, 16, 16};
    const int L = blockIdx.y;
    const int CI = CIs[L], CO = COs[L], COP = COPs[L];
    const int K = 27 * CI, KP = (K + 31) & ~31;
    const int total = COP * KP;
    for (int i = blockIdx.x * 256 + threadIdx.x; i < total; i += gridDim.x * 256) {
        int jp = i / KP;          // out channel (padded)
        int kp = i - jp * KP;     // k (padded)
        float v = (jp < CO && kp < K) ? a.W[L][(size_t)kp * CO + jp] : 0.f;
        a.dst[L][((size_t)(kp >> 5) * COP + jp) * 32 + (kp & 31)] = (HALF)v;
    }
}

__global__ void convert_x_kernel(const float* __restrict__ x, HALF* __restrict__ xh, int total)
{
    int i = blockIdx.x * 256 + threadIdx.x;
    if (i < total) xh[i] = (HALF)x[i];
}

// ---- bn_prep: fold the 8-way striped sum/sumsq into per-channel scale/bias once per layer
__global__ void bn_prep_kernel(const float* __restrict__ sums, const float* __restrict__ g,
                               const float* __restrict__ b, float invn, int CO, int COP,
                               float* __restrict__ scbi)
{
    const int c = threadIdx.x;
    if (c >= CO) return;
    float s = 0.f, q = 0.f;
#pragma unroll
    for (int k = 0; k < 8; ++k) { s += sums[k * 128 + c]; q += sums[k * 128 + COP + c]; }
    const float mu  = s * invn;
    const float var = q * invn - mu * mu;
    const float sc  = rsqrtf(var + 1e-3f) * g[c];
    scbi[c]       = sc;
    scbi[128 + c] = b[c] - mu * sc;
}

// ---- conv: CO-split across waves (L1-miss-count attack).
// Evidence rounds 0-6: 64ch layers pinned at 77us across occupancy 25-37% and 4x
// different B-traffic -> bound by per-CU L1 miss concurrency, not waves/latency.
// Fix 1: the block's waves share the SAME rows + SAME kc loop, each owning a
// 16-out-channel slice (WC waves). Identical A-gathers in near-lockstep -> one
// wave misses, the rest hit L1 (A misses / WC). Per-wave body = the proven
// round-2 loop with NJB=1 (acc 8 VGPR).
// Fix 2: B-fragment loads nontemporal (no L1 allocate) -> the 216KB/block weight
// stream stops evicting the A neighbor-row working set. y stores nontemporal.
// Barrier-free, zero LDS; stats via 8-way striped atomics.
// XCD-swizzled blockIdx: contiguous row ranges share an XCD L2.
template<int CI, int CO_PAD, int WC, bool FUSED>
__global__ __launch_bounds__(256, 2) void conv_kernel(
    const HALF* __restrict__ h, const int* __restrict__ nbr,
    const HALF* __restrict__ Wt, HALF* __restrict__ yout,
    float* __restrict__ sums, int n,
    const float* __restrict__ pscbi)
{
    constexpr int NMT  = 2;
    constexpr int K    = 27 * CI;
    constexpr int KP   = (K + 31) & ~31;
    constexpr int NCH  = KP / 32;
    constexpr int WR   = 4 / WC;                  // row-split ways
    constexpr int ROWS = WR * 32;                 // rows per block
    constexpr int LWC  = (WC == 4) ? 2 : ((WC == 2) ? 1 : 0);
    constexpr int NCB  = (CI >= 64) ? 2 : 1;
    constexpr int LOG2CI = (CI == 64) ? 6 : ((CI == 32) ? 5 : 4);

    const int wv   = threadIdx.x >> 6;
    const int lane = threadIdx.x & 63;
    const int l15  = lane & 15;
    const int lq   = lane >> 4;
    const int wc   = wv & (WC - 1);               // out-channel slice
    const int wr   = wv >> LWC;                   // row sub-block

    // bijective XCD swizzle (8 XCDs): contiguous block chunks land on one XCD
    int bid = blockIdx.x;
    {
        const int nwg = gridDim.x;
        const int q = nwg >> 3, r = nwg & 7;
        const int xcd = bid & 7, idx = bid >> 3;
        bid = (xcd < r ? xcd * (q + 1) : r * (q + 1) + (xcd - r) * q) + idx;
    }
    const int rowBase = bid * ROWS + wr * 32;     // this wave's 32 rows
    const int co0     = wc * 16;                  // this wave's 16 out channels

    f32x4 acc[NMT];
#pragma unroll
    for (int mt = 0; mt < NMT; ++mt)
#pragma unroll
        for (int r = 0; r < 4; ++r) acc[mt][r] = 0.f;

    int  nbo[NMT];
    bool rok[NMT];
#pragma unroll
    for (int mt = 0; mt < NMT; ++mt) {
        const int row = rowBase + mt * 16 + l15;
        rok[mt] = row < n;
        nbo[mt] = min(row, n - 1) * 27;
    }

    // per-lane normalization constants: precomputed by bn_prep, consecutive loads
    f16x8 sc8[NCB], bi8[NCB];
    if constexpr (FUSED) {
#pragma unroll
        for (int cb = 0; cb < NCB; ++cb) {
            const int c0 = cb * 32 + ((lq * 8) & (CI - 1));
#pragma unroll
            for (int j = 0; j < 8; ++j) {
                sc8[cb][j] = (HALF)pscbi[c0 + j];
                bi8[cb][j] = (HALF)pscbi[128 + c0 + j];
            }
        }
    }

    #define TAPOF(kc_) ((CI == 16) ? (2 * (kc_) + (lq >> 1)) : ((CI == 64) ? ((kc_) >> 1) : (kc_)))
    #define CHOF(kc_)  ((((kc_) * 32) + lq * 8) & (CI - 1))

    // ---- 2-deep rolling pipeline (round-2 body, NJB=1)
    int   ipf[2][NMT];
    f16x8 apf[2][NMT];
#pragma unroll
    for (int p = 0; p < 2; ++p) {
#pragma unroll
        for (int mt = 0; mt < NMT; ++mt) {
            const int t   = TAPOF(p);
            const int v   = nbr[nbo[mt] + (t < 27 ? t : 26)];
            const int idx = (rok[mt] && t < 27) ? v : -1;
            ipf[p][mt] = idx;
            apf[p][mt] = *(const f16x8*)(h + ((max(idx, 0) << LOG2CI) + CHOF(p)));
        }
    }

#pragma unroll
    for (int kc = 0; kc < NCH; ++kc) {
        const int cur = kc & 1;                   // compile-time (full unroll)
        const int ccb = (NCB == 2) ? (kc & 1) : 0;

        // B fragment for this wave's 16-co slice: NONTEMPORAL (don't pollute L1)
        const HALF* wb = Wt + (size_t)kc * (CO_PAD * 32) + (size_t)(co0 + l15) * 32 + lq * 8;
        const f16x8 b = __builtin_nontemporal_load((const f16x8*)wb);

        // take current stage
        f16x8 a_use[NMT];
        int   i_use[NMT];
#pragma unroll
        for (int mt = 0; mt < NMT; ++mt) { a_use[mt] = apf[cur][mt]; i_use[mt] = ipf[cur][mt]; }

        // refill stage with kc+2
        if (kc + 2 < NCH) {
#pragma unroll
            for (int mt = 0; mt < NMT; ++mt) {
                const int t   = TAPOF(kc + 2);
                const int v   = nbr[nbo[mt] + (t < 27 ? t : 26)];
                const int idx = (rok[mt] && t < 27) ? v : -1;
                ipf[cur][mt] = idx;
                apf[cur][mt] = *(const f16x8*)(h + ((max(idx, 0) << LOG2CI) + CHOF(kc + 2)));
            }
        }

        // consume
#pragma unroll
        for (int mt = 0; mt < NMT; ++mt) {
            f16x8 a = a_use[mt];
            if constexpr (FUSED) {
                a = a * sc8[ccb] + bi8[ccb];      // v_pk_fma_f16
#pragma unroll
                for (int j = 0; j < 8; ++j)
                    a[j] = (a[j] < (HALF)0.f) ? (HALF)0.f : a[j];
            }
            // zero invalid lanes AFTER bn so invalid -> exact 0
            const int m = ~(i_use[mt] >> 31);
            i32x4 ai = __builtin_bit_cast(i32x4, a);
            ai.x &= m; ai.y &= m; ai.z &= m; ai.w &= m;
            a = __builtin_bit_cast(f16x8, ai);
            acc[mt] = __builtin_amdgcn_mfma_f32_16x16x32_f16(a, b, acc[mt], 0, 0, 0);
        }
    }
    #undef TAPOF
    #undef CHOF

    // ---- epilogue (per wave, barrier-free): store RAW pre-norm y + striped stats
    // C/D layout: col = lane&15, row = (lane>>4)*4 + reg
    float* sl = sums + (bid & 7) * 128;
    const int col = co0 + l15;
    float s = 0.f, sq = 0.f;
#pragma unroll
    for (int mt = 0; mt < NMT; ++mt) {
        const int rb = rowBase + mt * 16 + lq * 4;
#pragma unroll
        for (int r = 0; r < 4; ++r) {
            if (rb + r < n) {
                const float v = acc[mt][r];
                __builtin_nontemporal_store((HALF)v, &yout[(size_t)(rb + r) * CO_PAD + col]);
                s += v;
                sq += v * v;
            }
        }
    }
    s  += __shfl_xor(s, 16);  s  += __shfl_xor(s, 32);
    sq += __shfl_xor(sq, 16); sq += __shfl_xor(sq, 32);
    if (lane < 16) {
        atomicAdd(&sl[col], s);
        atomicAdd(&sl[CO_PAD + col], sq);
    }
}

// ---- final: normalize (no relu), co=3 out of CO_PAD=16, fp32 output; striped sums
__global__ void bn_out_kernel(const HALF* __restrict__ y, const float* __restrict__ sums,
                              const float* __restrict__ g, const float* __restrict__ b,
                              int n, float invn, float* __restrict__ out)
{
    int i = blockIdx.x * 256 + threadIdx.x;
    if (i >= n * 3) return;
    int row = i / 3;
    int c = i - row * 3;
    float ssum = 0.f, qsum = 0.f;
#pragma unroll
    for (int k2 = 0; k2 < 8; ++k2) {
        ssum += sums[k2 * 128 + c];
        qsum += sums[k2 * 128 + 16 + c];
    }
    float mu  = ssum * invn;
    float var = qsum * invn - mu * mu;
    float sc  = rsqrtf(var + 1e-3f) * g[c];
    out[i] = ((float)y[(size_t)row * 16 + c] - mu) * sc + b[c];
}

extern "C" void kernel_launch(void* const* d_in, const int* in_sizes, int n_in,
                              void* d_out, int out_size, void* d_ws, size_t ws_size,
                              hipStream_t stream)
{
    const int* nbr4  = (const int*)d_in[0];
    const int* inv43 = (const int*)d_in[1];
    const int* nbr3  = (const int*)d_in[2];
    const int* inv32 = (const int*)d_in[3];
    const int* nbr2  = (const int*)d_in[4];
    const int* inv21 = (const int*)d_in[5];
    const int* nbr1  = (const int*)d_in[6];
    const float* x   = (const float*)d_in[7];

    const int n4 = in_sizes[0] / 27;
    const int n3 = in_sizes[1] / 27;
    const int n2 = in_sizes[3] / 27;
    const int n1 = in_sizes[5] / 27;

    // specs: m4,i4,m3,i3,m2,i2,m1,c5
    const int CIs[8]  = {64, 64, 64, 64, 32, 32, 16, 16};
    const int COs[8]  = {64, 64, 64, 32, 32, 16, 16, 3};
    const int COPs[8] = {64, 64, 64, 32, 32, 16, 16, 16};
    int KPs[8], wtoff[8];
    int wtot = 0;
    for (int s = 0; s < 8; ++s) {
        KPs[s] = ((27 * CIs[s] + 31) / 32) * 32;
        wtoff[s] = wtot;
        wtot += COPs[s] * KPs[s];
    }

    char* ws = (char*)d_ws;
    HALF* wt = (HALF*)ws;
    size_t off = ((size_t)wtot * sizeof(HALF) + 255) & ~(size_t)255;
    float* sums = (float*)(ws + off);
    off += 8 * 1024 * sizeof(float);              // 8 layers x 8 slots x 128 floats
    off = (off + 255) & ~(size_t)255;
    float* scbi = (float*)(ws + off);
    off += 8 * 256 * sizeof(float);               // 8 layers x {scale[128], bias[128]}
    off = (off + 255) & ~(size_t)255;
    HALF* xh = (HALF*)(ws + off);
    off += ((size_t)n4 * 64 * sizeof(HALF) + 255) & ~(size_t)255;
    size_t bufElems = 0;
    {
        size_t cand[4] = {(size_t)n4 * 64, (size_t)n3 * 64, (size_t)n2 * 32, (size_t)n1 * 16};
        for (int i = 0; i < 4; ++i) if (cand[i] > bufElems) bufElems = cand[i];
    }
    HALF* Y0 = (HALF*)(ws + off);
    off += (bufElems * sizeof(HALF) + 255) & ~(size_t)255;
    HALF* Y1 = (HALF*)(ws + off);

    hipMemsetAsync(sums, 0, 8 * 1024 * sizeof(float), stream);

    WArgs wa;
    for (int s = 0; s < 8; ++s) { wa.W[s] = (const float*)d_in[8 + 3 * s]; wa.dst[s] = wt + wtoff[s]; }
    {
        int maxTotal = 64 * KPs[0];
        dim3 grid((maxTotal + 255) / 256, 8);
        convert_all_w_kernel<<<grid, 256, 0, stream>>>(wa);
    }
    convert_x_kernel<<<(n4 * 64 + 255) / 256, 256, 0, stream>>>(x, xh, n4 * 64);

#define G(s) ((const float*)d_in[9 + 3 * (s)])
#define B(s) ((const float*)d_in[10 + 3 * (s)])
#define SUMS(s) (sums + (s) * 1024)
#define SCBI(s) (scbi + (s) * 256)
#define GRIDR(nn, rows) (((nn) + (rows) - 1) / (rows))
#define PREP(s, invn) bn_prep_kernel<<<1, 128, 0, stream>>>(SUMS(s), G(s), B(s), (invn), COs[s], COPs[s], SCBI(s))

    // m4: xh(n4,64) -> Y0 (raw); WC=4 (32 rows/block, 4 co-slices)
    conv_kernel<64, 64, 4, false><<<GRIDR(n4, 32), 256, 0, stream>>>(
        xh, nbr4, wt + wtoff[0], Y0, SUMS(0), n4, nullptr);
    PREP(0, 1.f / n4);
    // i4: norm(m4) fused; Y0(n4) -> Y1(n3)
    conv_kernel<64, 64, 4, true><<<GRIDR(n3, 32), 256, 0, stream>>>(
        Y0, inv43, wt + wtoff[1], Y1, SUMS(1), n3, SCBI(0));
    PREP(1, 1.f / n3);
    // m3: norm(i4) fused; Y1 -> Y0
    conv_kernel<64, 64, 4, true><<<GRIDR(n3, 32), 256, 0, stream>>>(
        Y1, nbr3, wt + wtoff[2], Y0, SUMS(2), n3, SCBI(1));
    PREP(2, 1.f / n3);
    // i3: norm(m3) fused; Y0(n3) -> Y1(n2), co 32; WC=2 (64 rows/block)
    conv_kernel<64, 32, 2, true><<<GRIDR(n2, 64), 256, 0, stream>>>(
        Y0, inv32, wt + wtoff[3], Y1, SUMS(3), n2, SCBI(2));
    PREP(3, 1.f / n2);
    // m2: norm(i3) fused; Y1 -> Y0
    conv_kernel<32, 32, 2, true><<<GRIDR(n2, 64), 256, 0, stream>>>(
        Y1, nbr2, wt + wtoff[4], Y0, SUMS(4), n2, SCBI(3));
    PREP(4, 1.f / n2);
    // i2: norm(m2) fused; Y0(n2) -> Y1(n1), co 16; WC=1 (128 rows/block)
    conv_kernel<32, 16, 1, true><<<GRIDR(n1, 128), 256, 0, stream>>>(
        Y0, inv21, wt + wtoff[5], Y1, SUMS(5), n1, SCBI(4));
    PREP(5, 1.f / n1);
    // m1: norm(i2) fused; Y1 -> Y0
    conv_kernel<16, 16, 1, true><<<GRIDR(n1, 128), 256, 0, stream>>>(
        Y1, nbr1, wt + wtoff[6], Y0, SUMS(6), n1, SCBI(5));
    PREP(6, 1.f / n1);
    // c5: norm(m1) fused; Y0 -> Y1 (raw), then fp32 out
    conv_kernel<16, 16, 1, true><<<GRIDR(n1, 128), 256, 0, stream>>>(
        Y0, nbr1, wt + wtoff[7], Y1, SUMS(7), n1, SCBI(6));
    bn_out_kernel<<<(n1 * 3 + 255) / 256, 256, 0, stream>>>(
        Y1, SUMS(7), G(7), B(7), n1, 1.f / n1, (float*)d_out);

#undef G
#undef B
#undef SUMS
#undef SCBI
#undef GRIDR
#undef PREP
}

// Round 8
// 549.241 us; speedup vs baseline: 1.3957x; 1.3957x over previous
//
#include <hip/hip_runtime.h>

typedef _Float16 HALF;
typedef _Float16 f16x8 __attribute__((ext_vector_type(8)));
typedef float f32x4 __attribute__((ext_vector_type(4)));
typedef int i32x4 __attribute__((ext_vector_type(4)));

__host__ __device__ inline int padded_kp(int CI, int CKC)
{
    int nch  = (27 * CI + 31) / 32;
    int nchp = ((nch + CKC - 1) / CKC) * CKC;
    return nchp * 32;
}

// ---- fused weight conversion: fp32 (27*CI, CO) -> fp16 tiled [KP/32][CO_PAD][32],
// zero padded BOTH in co and in k up to a CKC-multiple of 32-k tiles (so the conv
// kernel can stage fixed-size chunks with no tail logic).
struct WArgs { const float* W[8]; HALF* dst[8]; };

__global__ void convert_all_w_kernel(WArgs a)
{
    const int CIs[8]  = {64, 64, 64, 64, 32, 32, 16, 16};
    const int COs[8]  = {64, 64, 64, 32, 32, 16, 16, 3};
    const int COPs[8] = {64, 64, 64, 32, 32, 16, 16, 16};
    const int CKCs[8] = {6, 6, 6, 6, 4, 4, 4, 4};
    const int L = blockIdx.y;
    const int CI = CIs[L], CO = COs[L], COP = COPs[L];
    const int K = 27 * CI;
    const int KP = padded_kp(CI, CKCs[L]);
    const int total = COP * KP;
    for (int i = blockIdx.x * 256 + threadIdx.x; i < total; i += gridDim.x * 256) {
        int jp = i / KP;          // out channel (padded)
        int kp = i - jp * KP;     // k (padded)
        float v = (jp < CO && kp < K) ? a.W[L][(size_t)kp * CO + jp] : 0.f;
        a.dst[L][((size_t)(kp >> 5) * COP + jp) * 32 + (kp & 31)] = (HALF)v;
    }
}

__global__ void convert_x_kernel(const float* __restrict__ x, HALF* __restrict__ xh, int total)
{
    int i = blockIdx.x * 256 + threadIdx.x;
    if (i < total) xh[i] = (HALF)x[i];
}

// ---- bn_prep: fold the 8-way striped sum/sumsq into per-channel scale/bias once per layer
__global__ void bn_prep_kernel(const float* __restrict__ sums, const float* __restrict__ g,
                               const float* __restrict__ b, float invn, int CO, int COP,
                               float* __restrict__ scbi)
{
    const int c = threadIdx.x;
    if (c >= CO) return;
    float s = 0.f, q = 0.f;
#pragma unroll
    for (int k = 0; k < 8; ++k) { s += sums[k * 128 + c]; q += sums[k * 128 + COP + c]; }
    const float mu  = s * invn;
    const float var = q * invn - mu * mu;
    const float sc  = rsqrtf(var + 1e-3f) * g[c];
    scbi[c]       = sc;
    scbi[128 + c] = b[c] - mu * sc;
}

// ---- conv: VMEM-request-minimized gather-GEMM.
// Calibrated model (rounds 0-7): dur = ~2.4 cyc x VMEM 64B-segments per CU,
// independent of occupancy. So: (1) B weights staged to LDS once per block in
// CKC-kc double-buffered chunks (coalesced loads; 4 waves ds_read - removes the
// 4x redundant per-wave B VMEM, the largest request class); (2) neighbor indices
// staged to LDS coalesced (removes the 16-segment scattered idx loads);
// (3) A-gathers unchanged (irreducible); (4) ONE __syncthreads per chunk - the
// staging for chunk+1 issues at chunk top, its latency hides under this chunk's
// compute, and the barrier's natural vmcnt drain lands exactly when needed.
// Per-wave body = the proven round-2 compiler-scheduled loop. No inline asm.
// XCD-swizzled blockIdx: contiguous row ranges share an XCD L2.
template<int CI, int CO_PAD, int CKC, bool FUSED>
__global__ __launch_bounds__(256, 2) void conv_kernel(
    const HALF* __restrict__ h, const int* __restrict__ nbr,
    const HALF* __restrict__ Wt, HALF* __restrict__ yout,
    float* __restrict__ sums, int n,
    const float* __restrict__ pscbi)
{
    constexpr int K      = 27 * CI;
    constexpr int NCH    = (K + 31) / 32;
    constexpr int NCHP   = ((NCH + CKC - 1) / CKC) * CKC;   // padded (zero B tiles)
    constexpr int NCHUNK = NCHP / CKC;
    constexpr int NJB    = CO_PAD / 16;
    constexpr int NMT    = 2;
    constexpr int ROWS   = 128;
    constexpr int NCB    = (CI >= 64) ? 2 : 1;
    static_assert(NCB == 1 || (CKC & 1) == 0, "chunk must keep channel-half parity");
    constexpr int LOG2CI = (CI == 64) ? 6 : ((CI == 32) ? 5 : 4);
    constexpr int TPK    = CO_PAD * 32;            // halfwords per kc tile
    constexpr int CHW    = CKC * TPK;              // halfwords per chunk
    constexpr int NLD    = (CHW * 2) / 4096;       // 16B loads per thread per chunk
    static_assert(NLD * 4096 == CHW * 2, "chunk must be a multiple of 4KB");
    constexpr bool GUARD = (CI == 16) || (NCHP > NCH);

    __shared__ int  lidx[ROWS * 27];
    __shared__ HALF bbuf[2][CHW];

    const int wv   = threadIdx.x >> 6;
    const int lane = threadIdx.x & 63;
    const int l15  = lane & 15;
    const int lq   = lane >> 4;

    // bijective XCD swizzle (8 XCDs): contiguous block chunks land on one XCD
    int bid = blockIdx.x;
    {
        const int nwg = gridDim.x;
        const int q = nwg >> 3, r = nwg & 7;
        const int xcd = bid & 7, idx = bid >> 3;
        bid = (xcd < r ? xcd * (q + 1) : r * (q + 1) + (xcd - r) * q) + idx;
    }
    const int rowBase = bid * ROWS;
    const int waveRow = rowBase + wv * 32;         // this wave's 32 rows (row-split)

    // ---- stage neighbor indices to LDS (coalesced dwords; OOB rows -> -1)
    for (int i = threadIdx.x; i < ROWS * 27; i += 256) {
        const int r   = i / 27;
        const int row = rowBase + r;
        lidx[i] = (row < n) ? nbr[(size_t)row * 27 + (i - r * 27)] : -1;
    }
    // ---- stage B chunk 0
    {
        const i32x4* src = (const i32x4*)Wt;
        i32x4* dst = (i32x4*)(&bbuf[0][0]);
#pragma unroll
        for (int j = 0; j < NLD; ++j)
            dst[j * 256 + threadIdx.x] = src[j * 256 + threadIdx.x];
    }

    f32x4 acc[NMT][NJB];
#pragma unroll
    for (int mt = 0; mt < NMT; ++mt)
#pragma unroll
        for (int jb = 0; jb < NJB; ++jb)
#pragma unroll
            for (int r = 0; r < 4; ++r) acc[mt][jb][r] = 0.f;

    int lb[NMT];
#pragma unroll
    for (int mt = 0; mt < NMT; ++mt) lb[mt] = (wv * 32 + mt * 16 + l15) * 27;

    // per-lane normalization constants: precomputed by bn_prep, consecutive loads
    f16x8 sc8[NCB], bi8[NCB];
    if constexpr (FUSED) {
#pragma unroll
        for (int cb = 0; cb < NCB; ++cb) {
            const int c0 = cb * 32 + ((lq * 8) & (CI - 1));
#pragma unroll
            for (int j = 0; j < 8; ++j) {
                sc8[cb][j] = (HALF)pscbi[c0 + j];
                bi8[cb][j] = (HALF)pscbi[128 + c0 + j];
            }
        }
    }

    __syncthreads();                               // idx + chunk 0 visible

    for (int ch = 0; ch < NCHUNK; ++ch) {
        const HALF* bb = &bbuf[ch & 1][0];

        // stage chunk ch+1 (issues early; latency hidden under this chunk's compute)
        if (ch + 1 < NCHUNK) {
            const i32x4* src = (const i32x4*)(Wt + (size_t)(ch + 1) * CHW);
            i32x4* dst = (i32x4*)(&bbuf[(ch + 1) & 1][0]);
#pragma unroll
            for (int j = 0; j < NLD; ++j)
                dst[j * 256 + threadIdx.x] = src[j * 256 + threadIdx.x];
        }

#pragma unroll
        for (int kcc = 0; kcc < CKC; ++kcc) {
            const int kc  = ch * CKC + kcc;
            const int ccb = (NCB == 2) ? (kcc & 1) : 0;         // compile-time
            const int c   = (CI == 64) ? ((kcc & 1) * 32 + lq * 8)
                          : (CI == 32) ? (lq * 8)
                          : ((lq & 1) * 8);                      // compile-time

            // B fragments from LDS (lgkm pipe - off the VMEM request path)
            f16x8 b[NJB];
#pragma unroll
            for (int jb = 0; jb < NJB; ++jb)
                b[jb] = *(const f16x8*)(bb + kcc * TPK + (jb * 16 + l15) * 32 + lq * 8);

#pragma unroll
            for (int mt = 0; mt < NMT; ++mt) {
                const int t = (CI == 16) ? (2 * kc + (lq >> 1))
                            : (CI == 64) ? (kc >> 1) : kc;
                int idx;
                if constexpr (GUARD) idx = (t < 27) ? lidx[lb[mt] + t] : -1;
                else                 idx = lidx[lb[mt] + t];

                f16x8 a = *(const f16x8*)(h + ((max(idx, 0) << LOG2CI) + c));
                if constexpr (FUSED) {
                    a = a * sc8[ccb] + bi8[ccb];   // v_pk_fma_f16
#pragma unroll
                    for (int j = 0; j < 8; ++j)
                        a[j] = (a[j] < (HALF)0.f) ? (HALF)0.f : a[j];
                }
                // zero invalid taps AFTER bn so invalid -> exact 0
                const int m = ~(idx >> 31);
                i32x4 ai = __builtin_bit_cast(i32x4, a);
                ai.x &= m; ai.y &= m; ai.z &= m; ai.w &= m;
                a = __builtin_bit_cast(f16x8, ai);
#pragma unroll
                for (int jb = 0; jb < NJB; ++jb)
                    acc[mt][jb] = __builtin_amdgcn_mfma_f32_16x16x32_f16(a, b[jb], acc[mt][jb], 0, 0, 0);
            }
        }
        __syncthreads();                           // chunk ch+1 staged; bbuf[ch&1] free
    }

    // ---- epilogue (per wave, disjoint rows): store RAW pre-norm y + striped stats
    // C/D layout: col = lane&15, row = (lane>>4)*4 + reg
    float* sl = sums + (bid & 7) * 128;
#pragma unroll
    for (int jb = 0; jb < NJB; ++jb) {
        const int col = jb * 16 + l15;
        float s = 0.f, sq = 0.f;
#pragma unroll
        for (int mt = 0; mt < NMT; ++mt) {
            const int rb = waveRow + mt * 16 + lq * 4;
#pragma unroll
            for (int r = 0; r < 4; ++r) {
                if (rb + r < n) {
                    const float v = acc[mt][jb][r];
                    yout[(size_t)(rb + r) * CO_PAD + col] = (HALF)v;
                    s += v;
                    sq += v * v;
                }
            }
        }
        s  += __shfl_xor(s, 16);  s  += __shfl_xor(s, 32);
        sq += __shfl_xor(sq, 16); sq += __shfl_xor(sq, 32);
        if (lane < 16) {
            atomicAdd(&sl[col], s);
            atomicAdd(&sl[CO_PAD + col], sq);
        }
    }
}

// ---- final: normalize (no relu), co=3 out of CO_PAD=16, fp32 output; striped sums
__global__ void bn_out_kernel(const HALF* __restrict__ y, const float* __restrict__ sums,
                              const float* __restrict__ g, const float* __restrict__ b,
                              int n, float invn, float* __restrict__ out)
{
    int i = blockIdx.x * 256 + threadIdx.x;
    if (i >= n * 3) return;
    int row = i / 3;
    int c = i - row * 3;
    float ssum = 0.f, qsum = 0.f;
#pragma unroll
    for (int k2 = 0; k2 < 8; ++k2) {
        ssum += sums[k2 * 128 + c];
        qsum += sums[k2 * 128 + 16 + c];
    }
    float mu  = ssum * invn;
    float var = qsum * invn - mu * mu;
    float sc  = rsqrtf(var + 1e-3f) * g[c];
    out[i] = ((float)y[(size_t)row * 16 + c] - mu) * sc + b[c];
}

extern "C" void kernel_launch(void* const* d_in, const int* in_sizes, int n_in,
                              void* d_out, int out_size, void* d_ws, size_t ws_size,
                              hipStream_t stream)
{
    const int* nbr4  = (const int*)d_in[0];
    const int* inv43 = (const int*)d_in[1];
    const int* nbr3  = (const int*)d_in[2];
    const int* inv32 = (const int*)d_in[3];
    const int* nbr2  = (const int*)d_in[4];
    const int* inv21 = (const int*)d_in[5];
    const int* nbr1  = (const int*)d_in[6];
    const float* x   = (const float*)d_in[7];

    const int n4 = in_sizes[0] / 27;
    const int n3 = in_sizes[1] / 27;
    const int n2 = in_sizes[3] / 27;
    const int n1 = in_sizes[5] / 27;

    // specs: m4,i4,m3,i3,m2,i2,m1,c5
    const int CIs[8]  = {64, 64, 64, 64, 32, 32, 16, 16};
    const int COs[8]  = {64, 64, 64, 32, 32, 16, 16, 3};
    const int COPs[8] = {64, 64, 64, 32, 32, 16, 16, 16};
    const int CKCs[8] = {6, 6, 6, 6, 4, 4, 4, 4};
    int KPs[8], wtoff[8];
    int wtot = 0;
    for (int s = 0; s < 8; ++s) {
        KPs[s] = padded_kp(CIs[s], CKCs[s]);
        wtoff[s] = wtot;
        wtot += COPs[s] * KPs[s];
    }

    char* ws = (char*)d_ws;
    HALF* wt = (HALF*)ws;
    size_t off = ((size_t)wtot * sizeof(HALF) + 255) & ~(size_t)255;
    float* sums = (float*)(ws + off);
    off += 8 * 1024 * sizeof(float);              // 8 layers x 8 stripes x 128 floats
    off = (off + 255) & ~(size_t)255;
    float* scbi = (float*)(ws + off);
    off += 8 * 256 * sizeof(float);               // 8 layers x {scale[128], bias[128]}
    off = (off + 255) & ~(size_t)255;
    HALF* xh = (HALF*)(ws + off);
    off += ((size_t)n4 * 64 * sizeof(HALF) + 255) & ~(size_t)255;
    size_t bufElems = 0;
    {
        size_t cand[4] = {(size_t)n4 * 64, (size_t)n3 * 64, (size_t)n2 * 32, (size_t)n1 * 16};
        for (int i = 0; i < 4; ++i) if (cand[i] > bufElems) bufElems = cand[i];
    }
    HALF* Y0 = (HALF*)(ws + off);
    off += (bufElems * sizeof(HALF) + 255) & ~(size_t)255;
    HALF* Y1 = (HALF*)(ws + off);

    hipMemsetAsync(sums, 0, 8 * 1024 * sizeof(float), stream);

    WArgs wa;
    for (int s = 0; s < 8; ++s) { wa.W[s] = (const float*)d_in[8 + 3 * s]; wa.dst[s] = wt + wtoff[s]; }
    {
        int maxTotal = 64 * KPs[0];
        dim3 grid((maxTotal + 255) / 256, 8);
        convert_all_w_kernel<<<grid, 256, 0, stream>>>(wa);
    }
    convert_x_kernel<<<(n4 * 64 + 255) / 256, 256, 0, stream>>>(x, xh, n4 * 64);

#define G(s) ((const float*)d_in[9 + 3 * (s)])
#define B(s) ((const float*)d_in[10 + 3 * (s)])
#define SUMS(s) (sums + (s) * 1024)
#define SCBI(s) (scbi + (s) * 256)
#define GRID(nn) (((nn) + 127) / 128)
#define PREP(s, invn) bn_prep_kernel<<<1, 128, 0, stream>>>(SUMS(s), G(s), B(s), (invn), COs[s], COPs[s], SCBI(s))

    // m4: xh(n4,64) -> Y0 (raw)
    conv_kernel<64, 64, 6, false><<<GRID(n4), 256, 0, stream>>>(
        xh, nbr4, wt + wtoff[0], Y0, SUMS(0), n4, nullptr);
    PREP(0, 1.f / n4);
    // i4: norm(m4) fused; Y0(n4) -> Y1(n3)
    conv_kernel<64, 64, 6, true><<<GRID(n3), 256, 0, stream>>>(
        Y0, inv43, wt + wtoff[1], Y1, SUMS(1), n3, SCBI(0));
    PREP(1, 1.f / n3);
    // m3: norm(i4) fused; Y1 -> Y0
    conv_kernel<64, 64, 6, true><<<GRID(n3), 256, 0, stream>>>(
        Y1, nbr3, wt + wtoff[2], Y0, SUMS(2), n3, SCBI(1));
    PREP(2, 1.f / n3);
    // i3: norm(m3) fused; Y0(n3) -> Y1(n2), co 32
    conv_kernel<64, 32, 6, true><<<GRID(n2), 256, 0, stream>>>(
        Y0, inv32, wt + wtoff[3], Y1, SUMS(3), n2, SCBI(2));
    PREP(3, 1.f / n2);
    // m2: norm(i3) fused; Y1 -> Y0
    conv_kernel<32, 32, 4, true><<<GRID(n2), 256, 0, stream>>>(
        Y1, nbr2, wt + wtoff[4], Y0, SUMS(4), n2, SCBI(3));
    PREP(4, 1.f / n2);
    // i2: norm(m2) fused; Y0(n2) -> Y1(n1), co 16
    conv_kernel<32, 16, 4, true><<<GRID(n1), 256, 0, stream>>>(
        Y0, inv21, wt + wtoff[5], Y1, SUMS(5), n1, SCBI(4));
    PREP(5, 1.f / n1);
    // m1: norm(i2) fused; Y1 -> Y0
    conv_kernel<16, 16, 4, true><<<GRID(n1), 256, 0, stream>>>(
        Y1, nbr1, wt + wtoff[6], Y0, SUMS(6), n1, SCBI(5));
    PREP(6, 1.f / n1);
    // c5: norm(m1) fused; Y0 -> Y1 (raw), then fp32 out
    conv_kernel<16, 16, 4, true><<<GRID(n1), 256, 0, stream>>>(
        Y0, nbr1, wt + wtoff[7], Y1, SUMS(7), n1, SCBI(6));
    bn_out_kernel<<<(n1 * 3 + 255) / 256, 256, 0, stream>>>(
        Y1, SUMS(7), G(7), B(7), n1, 1.f / n1, (float*)d_out);

#undef G
#undef B
#undef SUMS
#undef SCBI
#undef GRID
#undef PREP
}